// Round 5
// baseline (6392.069 us; speedup 1.0000x reference)
//
#include <hip/hip_runtime.h>
#include <math.h>

#define BATCH 64
#define NREF  256
#define NPTS  2048
#define DIM   128
#define ITERS 100
#define INV_EPS 1000.0f
#define RCHUNK 16
#define NCHUNK (NREF / RCHUNK)   // 16 chunks of 16 rows

// Scaled (logit) domain throughout: u' = u/eps, v' = v/eps, C' = C/eps.

// ---------- C' via GEMM tiling + inline row norms ----------
// Block computes 128i x 128j of one batch. LDS rs[k][i], xs[k][j] (8x128).
// r2/x2 computed from the staging registers (pair-combine via shfl_xor 1).
__global__ __launch_bounds__(256) void cgemm_kernel(const float* __restrict__ X,
                                                    const float* __restrict__ ref,
                                                    float* __restrict__ C) {
    __shared__ float rs[8 * 128];
    __shared__ float xs[8 * 128];
    __shared__ float r2s[128];
    __shared__ float x2s[128];
    int b  = blockIdx.x >> 5;
    int it = (blockIdx.x >> 4) & 1;
    int jt = blockIdx.x & 15;
    int i0 = it * 128, j0 = jt * 128;
    int t  = threadIdx.x;
    int ti = t >> 4, tj = t & 15;

    int sr = t >> 1;                     // staging row 0..127
    int sh = (t & 1) * 4;                // k-offset 0 or 4
    const float* refp = ref + (size_t)(i0 + sr) * DIM + sh;
    const float* xp   = X + ((size_t)b * NPTS + j0 + sr) * DIM + sh;

    float4 acc[2][2][4];
#pragma unroll
    for (int p = 0; p < 2; ++p)
#pragma unroll
        for (int q = 0; q < 2; ++q)
#pragma unroll
            for (int ii = 0; ii < 4; ++ii)
                acc[p][q][ii] = make_float4(0.f, 0.f, 0.f, 0.f);
    float rsq = 0.f, xsq = 0.f;

    for (int k0 = 0; k0 < DIM; k0 += 8) {
        float4 rv = *(const float4*)(refp + k0);
        float4 xv = *(const float4*)(xp + k0);
        rsq += rv.x * rv.x + rv.y * rv.y + rv.z * rv.z + rv.w * rv.w;
        xsq += xv.x * xv.x + xv.y * xv.y + xv.z * xv.z + xv.w * xv.w;
        __syncthreads();                 // previous compute done before overwrite
        rs[(sh + 0) * 128 + sr] = rv.x; rs[(sh + 1) * 128 + sr] = rv.y;
        rs[(sh + 2) * 128 + sr] = rv.z; rs[(sh + 3) * 128 + sr] = rv.w;
        xs[(sh + 0) * 128 + sr] = xv.x; xs[(sh + 1) * 128 + sr] = xv.y;
        xs[(sh + 2) * 128 + sr] = xv.z; xs[(sh + 3) * 128 + sr] = xv.w;
        __syncthreads();

        const float4* rs4 = (const float4*)rs;
        const float4* xs4 = (const float4*)xs;
#pragma unroll
        for (int k = 0; k < 8; ++k) {
            float4 a0 = rs4[k * 32 + ti];
            float4 a1 = rs4[k * 32 + 16 + ti];
            float4 b0 = xs4[k * 32 + tj];
            float4 b1 = xs4[k * 32 + 16 + tj];
#define FMA4(ACC, S, BV)                                                     \
            ACC.x = fmaf(S, BV.x, ACC.x); ACC.y = fmaf(S, BV.y, ACC.y);      \
            ACC.z = fmaf(S, BV.z, ACC.z); ACC.w = fmaf(S, BV.w, ACC.w);
#define ROW(P, S, II)                                                        \
            FMA4(acc[P][0][II], S, b0) FMA4(acc[P][1][II], S, b1)
            ROW(0, a0.x, 0) ROW(0, a0.y, 1) ROW(0, a0.z, 2) ROW(0, a0.w, 3)
            ROW(1, a1.x, 0) ROW(1, a1.y, 1) ROW(1, a1.z, 2) ROW(1, a1.w, 3)
#undef ROW
#undef FMA4
        }
    }

    rsq += __shfl_xor(rsq, 1);           // combine the two k-halves of row sr
    xsq += __shfl_xor(xsq, 1);
    if ((t & 1) == 0) { r2s[sr] = rsq; x2s[sr] = xsq; }
    __syncthreads();

    float x2v[2][4];
#pragma unroll
    for (int q = 0; q < 2; ++q)
#pragma unroll
        for (int e = 0; e < 4; ++e)
            x2v[q][e] = x2s[q * 64 + tj * 4 + e];

#pragma unroll
    for (int p = 0; p < 2; ++p)
#pragma unroll
        for (int ii = 0; ii < 4; ++ii) {
            int il = p * 64 + ti * 4 + ii;
            float rr = r2s[il];
            float* crow = C + ((size_t)b * NREF + i0 + il) * NPTS + j0;
#pragma unroll
            for (int q = 0; q < 2; ++q) {
                float4 av = acc[p][q][ii];
                float4 o;
                o.x = sqrtf(fmaxf(rr + x2v[q][0] - 2.f * av.x, 0.f)) * INV_EPS;
                o.y = sqrtf(fmaxf(rr + x2v[q][1] - 2.f * av.y, 0.f)) * INV_EPS;
                o.z = sqrtf(fmaxf(rr + x2v[q][2] - 2.f * av.z, 0.f)) * INV_EPS;
                o.w = sqrtf(fmaxf(rr + x2v[q][3] - 2.f * av.w, 0.f)) * INV_EPS;
                *(float4*)(crow + q * 64 + tj * 4) = o;
            }
        }
}

// ---------- fused u+column-partial: 512 threads, thread owns ONE float4 col slot ----------
__global__ __launch_bounds__(512, 4) void uv_kernel(const float* __restrict__ C,
                                                    const float* __restrict__ v,
                                                    float* __restrict__ u,
                                                    float* __restrict__ Pl,
                                                    float log_wx) {
    __shared__ float smx[RCHUNK][8];
    __shared__ float sms[RCHUNK][8];
    int b     = blockIdx.x >> 4;
    int chunk = blockIdx.x & 15;
    int t     = threadIdx.x;
    int lane  = t & 63;
    int w     = t >> 6;

    const float* Cb = C + (size_t)(b * NREF + chunk * RCHUNK) * NPTS;
    float4 vj = *(const float4*)(v + (size_t)b * NPTS + 4 * t);

    float4 a[RCHUNK];
#pragma unroll
    for (int i = 0; i < RCHUNK; ++i)
        a[i] = *(const float4*)(Cb + (size_t)i * NPTS + 4 * t);

    float m[RCHUNK], su[RCHUNK];
#pragma unroll
    for (int i = 0; i < RCHUNK; ++i) {
        a[i].x = vj.x - a[i].x; a[i].y = vj.y - a[i].y;
        a[i].z = vj.z - a[i].z; a[i].w = vj.w - a[i].w;
        m[i] = fmaxf(fmaxf(a[i].x, a[i].y), fmaxf(a[i].z, a[i].w));
    }
#pragma unroll
    for (int i = 0; i < RCHUNK; ++i)
#pragma unroll
        for (int off = 1; off < 64; off <<= 1)
            m[i] = fmaxf(m[i], __shfl_xor(m[i], off));
    if (lane == 0) {
#pragma unroll
        for (int i = 0; i < RCHUNK; ++i) smx[i][w] = m[i];
    }
    __syncthreads();
#pragma unroll
    for (int i = 0; i < RCHUNK; ++i) {
        float mm = smx[i][0];
#pragma unroll
        for (int q = 1; q < 8; ++q) mm = fmaxf(mm, smx[i][q]);
        m[i] = mm;
    }
#pragma unroll
    for (int i = 0; i < RCHUNK; ++i)
        su[i] = __expf(a[i].x - m[i]) + __expf(a[i].y - m[i])
              + __expf(a[i].z - m[i]) + __expf(a[i].w - m[i]);
#pragma unroll
    for (int i = 0; i < RCHUNK; ++i)
#pragma unroll
        for (int off = 1; off < 64; off <<= 1)
            su[i] += __shfl_xor(su[i], off);
    if (lane == 0) {
#pragma unroll
        for (int i = 0; i < RCHUNK; ++i) sms[i][w] = su[i];
    }
    __syncthreads();
#pragma unroll
    for (int i = 0; i < RCHUNK; ++i) {
        float s = ((sms[i][0] + sms[i][1]) + (sms[i][2] + sms[i][3]))
                + ((sms[i][4] + sms[i][5]) + (sms[i][6] + sms[i][7]));
        su[i] = log_wx - (m[i] + __logf(s));    // su := u_new for row i
    }
    int ub = b * NREF + chunk * RCHUNK;
#pragma unroll
    for (int i = 0; i < RCHUNK; ++i)
        if (t == i) u[ub + i] = su[i];

    // column partial LSE over the 16 rows; arg = u - C = a + su - v_j
    float4 pl;
#define COLL(Q)                                                              \
    {                                                                        \
        float mq = a[0].Q + su[0];                                           \
        _Pragma("unroll")                                                    \
        for (int i_ = 1; i_ < RCHUNK; ++i_)                                  \
            mq = fmaxf(mq, a[i_].Q + su[i_]);                                \
        float sq_ = 0.f;                                                     \
        _Pragma("unroll")                                                    \
        for (int i_ = 0; i_ < RCHUNK; ++i_)                                  \
            sq_ += __expf(a[i_].Q + su[i_] - mq);                            \
        pl.Q = (mq - vj.Q) + __logf(sq_);                                    \
    }
    COLL(x) COLL(y) COLL(z) COLL(w)
#undef COLL
    *(float4*)(Pl + (size_t)(b * NCHUNK + chunk) * NPTS + 4 * t) = pl;
}

// ---------- merge 16 chunk logits per column -> v ----------
__global__ __launch_bounds__(256) void vmerge_kernel(const float* __restrict__ Pl,
                                                     float* __restrict__ v,
                                                     float log_wy) {
    int b = blockIdx.x >> 3;
    int j = ((blockIdx.x & 7) << 8) + threadIdx.x;
    const float* p = Pl + (size_t)b * NCHUNK * NPTS + j;
    float l[NCHUNK];
#pragma unroll
    for (int c = 0; c < NCHUNK; ++c) l[c] = p[(size_t)c * NPTS];
    float m = l[0];
#pragma unroll
    for (int c = 1; c < NCHUNK; ++c) m = fmaxf(m, l[c]);
    float s = 0.f;
#pragma unroll
    for (int c = 0; c < NCHUNK; ++c) s += __expf(l[c] - m);
    v[(size_t)b * NPTS + j] = log_wy - (m + __logf(s));
}

// ---------- epilogue phase 1: block = (b, 256-col chunk), 512 threads, ALL 256 rows ----------
// C and X each read exactly ONCE across the grid (disjoint j-chunks). Partial
// numerator / denominator accumulated into num/den via hardware fp32 atomics
// (device-scope, 8-way collisions max). wt staged XOR-swizzled by row-group.
__global__ __launch_bounds__(512, 4) void out_partial(const float* __restrict__ C,
                                                      const float* __restrict__ X,
                                                      const float* __restrict__ u,
                                                      const float* __restrict__ v,
                                                      float* __restrict__ num,
                                                      float* __restrict__ den) {
    __shared__ float wts[NREF * 32];    // [r][8 float4, swizzled]  32 KB
    __shared__ float xt[32 * DIM];      // [jj][d]                  16 KB
    int b  = blockIdx.x >> 3;
    int jc = blockIdx.x & 7;
    int j0 = jc * 256;
    int t  = threadIdx.x;
    int s  = t & 15;                    // d-slot
    int g  = t >> 4;                    // row group: rows g*8 .. g*8+7

    const float* Cb = C + (size_t)b * NREF * NPTS + j0;
    const float* ub = u + b * NREF;
    const float* vb = v + (size_t)b * NPTS + j0;

    float4 a0[8], a1[8];
    float ws[8];
#pragma unroll
    for (int r = 0; r < 8; ++r) {
        a0[r] = make_float4(0.f, 0.f, 0.f, 0.f);
        a1[r] = make_float4(0.f, 0.f, 0.f, 0.f);
        ws[r] = 0.f;
    }

    for (int jt = 0; jt < 256; jt += 32) {
        // stage wt: 256 rows x 32 cols = 2048 float4, 4 per thread (coalesced C)
#pragma unroll
        for (int k = 0; k < 4; ++k) {
            int fidx = t + 512 * k;
            int r = fidx >> 3, q = fidx & 7;
            float4 cv = *(const float4*)(Cb + (size_t)r * NPTS + jt + 4 * q);
            float4 vv = *(const float4*)(vb + jt + 4 * q);
            float uu = ub[r];
            float4 wv;
            wv.x = __expf(uu + vv.x - cv.x);
            wv.y = __expf(uu + vv.y - cv.y);
            wv.z = __expf(uu + vv.z - cv.z);
            wv.w = __expf(uu + vv.w - cv.w);
            int sw = q ^ ((r >> 3) & 7);
            *(float4*)&wts[r * 32 + sw * 4] = wv;
        }
        // stage X-tile: 32 rows x 128 d = 1024 float4, 2 per thread
        const float4* Xb4 = (const float4*)(X + ((size_t)b * NPTS + j0 + jt) * DIM);
        ((float4*)xt)[t]       = Xb4[t];
        ((float4*)xt)[t + 512] = Xb4[t + 512];
        __syncthreads();

        const float4* xt4 = (const float4*)xt;
#pragma unroll
        for (int jp = 0; jp < 16; ++jp) {       // jj = 2*jp, 2*jp+1
            int j1 = 2 * jp;
            float4 xa0 = xt4[j1 * 32 + s];
            float4 xa1 = xt4[j1 * 32 + 16 + s];
            float4 xb0 = xt4[(j1 + 1) * 32 + s];
            float4 xb1 = xt4[(j1 + 1) * 32 + 16 + s];
            int q   = jp >> 1;
            int h   = jp & 1;
            int swb = (q ^ (g & 7)) * 4 + 2 * h;   // float offset within row's 32
#pragma unroll
            for (int rr = 0; rr < 8; ++rr) {
                int r = g * 8 + rr;
                float2 w2 = *(const float2*)&wts[r * 32 + swb];
                a0[rr].x = fmaf(w2.x, xa0.x, a0[rr].x);
                a0[rr].y = fmaf(w2.x, xa0.y, a0[rr].y);
                a0[rr].z = fmaf(w2.x, xa0.z, a0[rr].z);
                a0[rr].w = fmaf(w2.x, xa0.w, a0[rr].w);
                a1[rr].x = fmaf(w2.x, xa1.x, a1[rr].x);
                a1[rr].y = fmaf(w2.x, xa1.y, a1[rr].y);
                a1[rr].z = fmaf(w2.x, xa1.z, a1[rr].z);
                a1[rr].w = fmaf(w2.x, xa1.w, a1[rr].w);
                a0[rr].x = fmaf(w2.y, xb0.x, a0[rr].x);
                a0[rr].y = fmaf(w2.y, xb0.y, a0[rr].y);
                a0[rr].z = fmaf(w2.y, xb0.z, a0[rr].z);
                a0[rr].w = fmaf(w2.y, xb0.w, a0[rr].w);
                a1[rr].x = fmaf(w2.y, xb1.x, a1[rr].x);
                a1[rr].y = fmaf(w2.y, xb1.y, a1[rr].y);
                a1[rr].z = fmaf(w2.y, xb1.z, a1[rr].z);
                a1[rr].w = fmaf(w2.y, xb1.w, a1[rr].w);
                ws[rr] += w2.x + w2.y;
            }
        }
        __syncthreads();
    }

    // accumulate partials: 64 fp32 atomics/thread (distinct addrs within block)
#pragma unroll
    for (int rr = 0; rr < 8; ++rr) {
        int r = g * 8 + rr;
        float* nrow = num + ((size_t)b * NREF + r) * DIM;
        unsafeAtomicAdd(nrow + 4 * s + 0, a0[rr].x);
        unsafeAtomicAdd(nrow + 4 * s + 1, a0[rr].y);
        unsafeAtomicAdd(nrow + 4 * s + 2, a0[rr].z);
        unsafeAtomicAdd(nrow + 4 * s + 3, a0[rr].w);
        unsafeAtomicAdd(nrow + 64 + 4 * s + 0, a1[rr].x);
        unsafeAtomicAdd(nrow + 64 + 4 * s + 1, a1[rr].y);
        unsafeAtomicAdd(nrow + 64 + 4 * s + 2, a1[rr].z);
        unsafeAtomicAdd(nrow + 64 + 4 * s + 3, a1[rr].w);
        if (s == 0) unsafeAtomicAdd(den + b * NREF + r, ws[rr]);
    }
}

// ---------- epilogue phase 2: out = num/den - ref ----------
__global__ __launch_bounds__(256) void out_finish(const float* __restrict__ num,
                                                  const float* __restrict__ den,
                                                  const float* __restrict__ ref,
                                                  float* __restrict__ out) {
    int fidx = blockIdx.x * 256 + threadIdx.x;      // float4 index, 524288 total
    int b = fidx >> 13;                             // 8192 float4 per batch
    int w = fidx & 8191;
    int i = w >> 5;                                 // row 0..255
    int q = w & 31;                                 // d-quad
    float4 n4 = ((const float4*)num)[fidx];
    float inv = 1.0f / (den[(b << 8) + i] + 1e-8f);
    float4 rf = ((const float4*)ref)[i * 32 + q];
    float4 o;
    o.x = n4.x * inv - rf.x;
    o.y = n4.y * inv - rf.y;
    o.z = n4.z * inv - rf.z;
    o.w = n4.w * inv - rf.w;
    ((float4*)out)[fidx] = o;
}

extern "C" void kernel_launch(void* const* d_in, const int* in_sizes, int n_in,
                              void* d_out, int out_size, void* d_ws, size_t ws_size,
                              hipStream_t stream) {
    const float* X   = (const float*)d_in[0];
    const float* ref = (const float*)d_in[1];
    float* out = (float*)d_out;

    char* ws = (char*)d_ws;
    size_t o = 0;
    float* C   = (float*)(ws + o); o += (size_t)BATCH * NREF * NPTS * sizeof(float);
    float* u   = (float*)(ws + o); o += (size_t)BATCH * NREF * sizeof(float);
    float* v   = (float*)(ws + o); o += (size_t)BATCH * NPTS * sizeof(float);
    float* Pl  = (float*)(ws + o); o += (size_t)BATCH * NCHUNK * NPTS * sizeof(float);
    float* den = (float*)(ws + o); o += (size_t)BATCH * NREF * sizeof(float);
    float* num = Pl;   // Pl (8 MB) is dead after the loop; num is exactly 8 MB

    const float log_wx = (float)log(1.0 / (double)NREF + 1e-8);
    const float log_wy = (float)log(1.0 / (double)NPTS + 1e-8);

    hipMemsetAsync(v, 0, (size_t)BATCH * NPTS * sizeof(float), stream);

    cgemm_kernel<<<BATCH * 32, 256, 0, stream>>>(X, ref, C);

    for (int t = 0; t < ITERS; ++t) {
        uv_kernel<<<BATCH * NCHUNK, 512, 0, stream>>>(C, v, u, Pl, log_wx);
        vmerge_kernel<<<BATCH * NPTS / 256, 256, 0, stream>>>(Pl, v, log_wy);
    }

    // zero num (aliases Pl) + den in one stream-ordered memset, then accumulate
    hipMemsetAsync(num, 0,
                   ((size_t)BATCH * NCHUNK * NPTS + (size_t)BATCH * NREF) * sizeof(float),
                   stream);
    out_partial<<<BATCH * 8, 512, 0, stream>>>(C, X, u, v, num, den);
    out_finish<<<BATCH * NREF * DIM / 1024, 256, 0, stream>>>(num, den, ref, out);
}